// Round 13
// baseline (341.193 us; speedup 1.0000x reference)
//
#include <hip/hip_runtime.h>
#include <math.h>

#define N_NODES   50000
#define N_EDGES   800000
#define IN_FEAT   64
#define HIDDEN    32
#define GRID_SZ   4
#define N_GRAPHS  128
#define NEG_SLOPE 0.01f
#define SCAN_BLOCKS 196   // ceil(50000/256)

// ---------------------------------------------------------------------------
__global__ __launch_bounds__(256) void zero_int_kernel(int* __restrict__ p, int n) {
  const int i = blockIdx.x * 256 + threadIdx.x;
  if (i < n) p[i] = 0;
}
__global__ __launch_bounds__(256) void zero_kernel(float* __restrict__ p, int n) {
  const int i = blockIdx.x * 256 + threadIdx.x;
  if (i < n) p[i] = 0.f;
}

// ---------------------------------------------------------------------------
// CSR build: histogram of dst into deg[]
// ---------------------------------------------------------------------------
__global__ __launch_bounds__(256) void hist_kernel(
    const int* __restrict__ dst, int* __restrict__ deg) {
  const int e = blockIdx.x * 256 + threadIdx.x;
  if (e < N_EDGES) atomicAdd(&deg[dst[e]], 1);
}

// multi-block scan, step A: per-block sums of deg -> bsum[SCAN_BLOCKS]
__global__ __launch_bounds__(256) void scanA_kernel(
    const int* __restrict__ deg, int* __restrict__ bsum) {
  const int i = blockIdx.x * 256 + threadIdx.x;
  int v = (i < N_NODES) ? deg[i] : 0;
#pragma unroll
  for (int o = 32; o > 0; o >>= 1) v += __shfl_down(v, o, 64);
  __shared__ int ws[4];
  if ((threadIdx.x & 63) == 0) ws[threadIdx.x >> 6] = v;
  __syncthreads();
  if (threadIdx.x == 0) bsum[blockIdx.x] = ws[0] + ws[1] + ws[2] + ws[3];
}

// step B: single small block scans the 196 block sums -> exclusive offsets
__global__ __launch_bounds__(256) void scanB_kernel(
    int* __restrict__ bsum, int* __restrict__ row_ptr) {
  __shared__ int sh[256];
  const int t = threadIdx.x;
  int v = (t < SCAN_BLOCKS) ? bsum[t] : 0;
  sh[t] = v;
  __syncthreads();
  for (int o = 1; o < 256; o <<= 1) {
    const int u = (t >= o) ? sh[t - o] : 0;
    __syncthreads();
    sh[t] += u;
    __syncthreads();
  }
  bsum[t] = (t == 0) ? 0 : sh[t - 1];   // exclusive
  if (t == 0) row_ptr[N_NODES] = N_EDGES;
}

// step C: per-block exclusive scan + block offset -> row_ptr, cursor
__global__ __launch_bounds__(256) void scanC_kernel(
    const int* __restrict__ deg, const int* __restrict__ bsum,
    int* __restrict__ row_ptr, int* __restrict__ cursor) {
  __shared__ int sh[256];
  const int t = threadIdx.x;
  const int i = blockIdx.x * 256 + t;
  const int v = (i < N_NODES) ? deg[i] : 0;
  sh[t] = v;
  __syncthreads();
  for (int o = 1; o < 256; o <<= 1) {
    const int u = (t >= o) ? sh[t - o] : 0;
    __syncthreads();
    sh[t] += u;
    __syncthreads();
  }
  if (i < N_NODES) {
    const int excl = bsum[blockIdx.x] + sh[t] - v;
    row_ptr[i] = excl;
    cursor[i] = excl;
  }
}

// fill: adj[pos] = src, pos = cursor[dst]++
__global__ __launch_bounds__(256) void fill_kernel(
    const int* __restrict__ src, const int* __restrict__ dst,
    int* __restrict__ cursor, int* __restrict__ adj) {
  const int e = blockIdx.x * 256 + threadIdx.x;
  if (e < N_EDGES) {
    const int pos = atomicAdd(&cursor[dst[e]], 1);
    adj[pos] = src[e];
  }
}

// ---------------------------------------------------------------------------
// gather + fused update, float4: 8 lanes/node, each lane owns 4 feats.
// H[n] = leaky(H[n] + sum_{k in row(n)} T[adj[k]])
// ---------------------------------------------------------------------------
__global__ __launch_bounds__(256) void gather_update_v2(
    const float* __restrict__ T, const int* __restrict__ row_ptr,
    const int* __restrict__ adj, float* __restrict__ H) {
  const int gid = blockIdx.x * 256 + threadIdx.x;
  const int n = gid >> 3;
  const int q = gid & 7;          // float4 slot within the 32-float row
  if (n >= N_NODES) return;
  const int lo = row_ptr[n], hi = row_ptr[n + 1];
  const float4* __restrict__ T4 = reinterpret_cast<const float4*>(T);
  float4 acc = make_float4(0.f, 0.f, 0.f, 0.f);
  for (int k = lo; k < hi; ++k) {
    const int s = adj[k];
    const float4 t = T4[s * 8 + q];
    acc.x += t.x; acc.y += t.y; acc.z += t.z; acc.w += t.w;
  }
  float4* __restrict__ H4 = reinterpret_cast<float4*>(H);
  float4 h = H4[n * 8 + q];
  h.x += acc.x; h.y += acc.y; h.z += acc.z; h.w += acc.w;
  h.x = (h.x >= 0.f) ? h.x : NEG_SLOPE * h.x;
  h.y = (h.y >= 0.f) ? h.y : NEG_SLOPE * h.y;
  h.z = (h.z >= 0.f) ? h.z : NEG_SLOPE * h.z;
  h.w = (h.w >= 0.f) ? h.w : NEG_SLOPE * h.w;
  H4[n * 8 + q] = h;
}

// ---------------------------------------------------------------------------
// Input KAN v10: 128 thr, block = (16 outputs half) x (128 nodes).
// thread = (oq in 0..3, grp in 0..31 -> 4 nodes). Trig per-thread in-register
// (no trig LDS, no stream barriers); weights-only LDS 32KB, XOR-swizzled.
// Per i-step: 8 weight b128 per 128 FMA; X via per-lane float4 (L1).
// ---------------------------------------------------------------------------
__global__ __launch_bounds__(128, 2) void kan_input_v10(
    const float* __restrict__ X, const float* __restrict__ W,
    float* __restrict__ H) {
  __shared__ float4 w4[2048];           // 32KB: [part][o_l][slot]
  const int tid = threadIdx.x;
  const int half = blockIdx.x & 1;      // output half: cols 16*half..
  const int nblk = blockIdx.x >> 1;
  const int n0 = nblk * 128;

  // stage this half's weights, swizzled: slot = i ^ (o_l>>2)
  const float4* __restrict__ Wg = reinterpret_cast<const float4*>(W);
#pragma unroll
  for (int r = 0; r < 16; ++r) {
    const int idx = r * 128 + tid;      // 0..2047
    const int part = idx >> 10;         // 0 = cos, 1 = sin
    const int rem = idx & 1023;
    const int o_l = rem >> 6;           // 0..15
    const int i = rem & 63;
    w4[part * 1024 + o_l * 64 + (i ^ (o_l >> 2))] =
        Wg[part * 2048 + (half * 16 + o_l) * 64 + i];
  }
  __syncthreads();

  const int oq = tid & 3;               // local o-quad: cols 4*oq..4*oq+3
  const int grp = tid >> 2;             // 0..31
  const int nb = 4 * grp;               // local node base

  // clamp node indices for loads
  int gs[4];
#pragma unroll
  for (int n = 0; n < 4; ++n) {
    const int gn = n0 + nb + n;
    gs[n] = (gn < N_NODES) ? gn : (N_NODES - 1);
  }

  float acc[4][4];
#pragma unroll
  for (int n = 0; n < 4; ++n)
#pragma unroll
    for (int q = 0; q < 4; ++q) acc[n][q] = 0.f;

  for (int ci = 0; ci < 16; ++ci) {     // 16 chunks of 4 i
    float4 xv[4];
#pragma unroll
    for (int n = 0; n < 4; ++n)
      xv[n] = reinterpret_cast<const float4*>(X + gs[n] * IN_FEAT)[ci];
#pragma unroll
    for (int j = 0; j < 4; ++j) {
      const int i = ci * 4 + j;
      float cN[4][4], sN[4][4];
#pragma unroll
      for (int n = 0; n < 4; ++n) {
        const float v = (j == 0) ? xv[n].x : (j == 1) ? xv[n].y :
                        (j == 2) ? xv[n].z : xv[n].w;
        float s1, c1;
        sincosf(v, &s1, &c1);
        const float c2 = c1*c1 - s1*s1, s2 = s1*c1 + c1*s1;
        const float c3 = c2*c1 - s2*s1, s3 = s2*c1 + c2*s1;
        const float c4 = c3*c1 - s3*s1, s4 = s3*c1 + c3*s1;
        cN[n][0]=c1; cN[n][1]=c2; cN[n][2]=c3; cN[n][3]=c4;
        sN[n][0]=s1; sN[n][1]=s2; sN[n][2]=s3; sN[n][3]=s4;
      }
      const int sl = i ^ oq;
#pragma unroll
      for (int q = 0; q < 4; ++q) {
        const float4 a = w4[(4 * oq + q) * 64 + sl];
        const float4 b = w4[1024 + (4 * oq + q) * 64 + sl];
#pragma unroll
        for (int n = 0; n < 4; ++n)
          acc[n][q] += cN[n][0]*a.x + cN[n][1]*a.y + cN[n][2]*a.z + cN[n][3]*a.w
                     + sN[n][0]*b.x + sN[n][1]*b.y + sN[n][2]*b.z + sN[n][3]*b.w;
      }
    }
  }
#pragma unroll
  for (int n = 0; n < 4; ++n) {
    const int gn = n0 + nb + n;
    if (gn < N_NODES)
      *reinterpret_cast<float4*>(&H[gn * HIDDEN + half * 16 + 4 * oq]) =
          make_float4(acc[n][0], acc[n][1], acc[n][2], acc[n][3]);
  }
}

// ---------------------------------------------------------------------------
// Conv KAN v10: same structure; 32 i; weights half = 16KB LDS.
// ---------------------------------------------------------------------------
__global__ __launch_bounds__(128, 2) void kan_node_v10(
    const float* __restrict__ Hin, const float* __restrict__ W,
    float* __restrict__ T) {
  __shared__ float4 w4[1024];           // 16KB
  const int tid = threadIdx.x;
  const int half = blockIdx.x & 1;
  const int nblk = blockIdx.x >> 1;
  const int n0 = nblk * 128;

  const float4* __restrict__ Wg = reinterpret_cast<const float4*>(W);
#pragma unroll
  for (int r = 0; r < 8; ++r) {
    const int idx = r * 128 + tid;      // 0..1023
    const int part = idx >> 9;          // 0 = cos, 1 = sin
    const int rem = idx & 511;
    const int o_l = rem >> 5;           // 0..15
    const int i = rem & 31;
    w4[part * 512 + o_l * 32 + (i ^ (o_l >> 2))] =
        Wg[part * 1024 + (half * 16 + o_l) * 32 + i];
  }
  __syncthreads();

  const int oq = tid & 3;
  const int grp = tid >> 2;
  const int nb = 4 * grp;

  int gs[4];
#pragma unroll
  for (int n = 0; n < 4; ++n) {
    const int gn = n0 + nb + n;
    gs[n] = (gn < N_NODES) ? gn : (N_NODES - 1);
  }

  float acc[4][4];
#pragma unroll
  for (int n = 0; n < 4; ++n)
#pragma unroll
    for (int q = 0; q < 4; ++q) acc[n][q] = 0.f;

  for (int ci = 0; ci < 8; ++ci) {      // 8 chunks of 4 i
    float4 xv[4];
#pragma unroll
    for (int n = 0; n < 4; ++n)
      xv[n] = reinterpret_cast<const float4*>(Hin + gs[n] * HIDDEN)[ci];
#pragma unroll
    for (int j = 0; j < 4; ++j) {
      const int i = ci * 4 + j;
      float cN[4][4], sN[4][4];
#pragma unroll
      for (int n = 0; n < 4; ++n) {
        const float v = (j == 0) ? xv[n].x : (j == 1) ? xv[n].y :
                        (j == 2) ? xv[n].z : xv[n].w;
        float s1, c1;
        sincosf(v, &s1, &c1);
        const float c2 = c1*c1 - s1*s1, s2 = s1*c1 + c1*s1;
        const float c3 = c2*c1 - s2*s1, s3 = s2*c1 + c2*s1;
        const float c4 = c3*c1 - s3*s1, s4 = s3*c1 + c3*s1;
        cN[n][0]=c1; cN[n][1]=c2; cN[n][2]=c3; cN[n][3]=c4;
        sN[n][0]=s1; sN[n][1]=s2; sN[n][2]=s3; sN[n][3]=s4;
      }
      const int sl = i ^ oq;
#pragma unroll
      for (int q = 0; q < 4; ++q) {
        const float4 a = w4[(4 * oq + q) * 32 + sl];
        const float4 b = w4[512 + (4 * oq + q) * 32 + sl];
#pragma unroll
        for (int n = 0; n < 4; ++n)
          acc[n][q] += cN[n][0]*a.x + cN[n][1]*a.y + cN[n][2]*a.z + cN[n][3]*a.w
                     + sN[n][0]*b.x + sN[n][1]*b.y + sN[n][2]*b.z + sN[n][3]*b.w;
      }
    }
  }
#pragma unroll
  for (int n = 0; n < 4; ++n) {
    const int gn = n0 + nb + n;
    if (gn < N_NODES)
      *reinterpret_cast<float4*>(&T[gn * HIDDEN + half * 16 + 4 * oq]) =
          make_float4(acc[n][0], acc[n][1], acc[n][2], acc[n][3]);
  }
}

// ---------------------------------------------------------------------------
// pool via run-length over sorted batch: thread = (range r, feat f)
// ---------------------------------------------------------------------------
#define POOL_RANGES 512
__global__ __launch_bounds__(256) void pool_rl(
    const float* __restrict__ H, const int* __restrict__ batch,
    float* __restrict__ sums, float* __restrict__ cnt) {
  const int tid = threadIdx.x;
  const int f = tid & 31;
  const int r = blockIdx.x * 8 + (tid >> 5);
  const int PER = (N_NODES + POOL_RANGES - 1) / POOL_RANGES;  // 98
  int n = r * PER;
  const int end = (n + PER < N_NODES) ? n + PER : N_NODES;
  if (n >= end) return;
  int g = batch[n];
  float acc = 0.f, c = 0.f;
  for (; n < end; ++n) {
    const int gn = batch[n];
    if (gn != g) {
      atomicAdd(&sums[g * HIDDEN + f], acc);
      if (f == 0) atomicAdd(&cnt[g], c);
      g = gn; acc = 0.f; c = 0.f;
    }
    acc += H[n * HIDDEN + f];
    c += 1.f;
  }
  atomicAdd(&sums[g * HIDDEN + f], acc);
  if (f == 0) atomicAdd(&cnt[g], c);
}

// ---------------------------------------------------------------------------
__global__ __launch_bounds__(128) void readout_kernel(
    const float* __restrict__ sums, const float* __restrict__ cnt,
    const float* __restrict__ Wout, const float* __restrict__ bout,
    float* __restrict__ out) {
  const int g = threadIdx.x;
  if (g < N_GRAPHS) {
    const float c = fmaxf(cnt[g], 1.0f);
    float z = 0.f;
#pragma unroll
    for (int i = 0; i < HIDDEN; ++i) {
      const float y = sums[g * HIDDEN + i] / c;
      z += cosf(y) * Wout[i] + sinf(y) * Wout[HIDDEN + i];
    }
    z += bout[0];
    out[g] = 1.0f / (1.0f + expf(-z));
  }
}

// ---------------------------------------------------------------------------
extern "C" void kernel_launch(void* const* d_in, const int* in_sizes, int n_in,
                              void* d_out, int out_size, void* d_ws, size_t ws_size,
                              hipStream_t stream) {
  const float* x        = (const float*)d_in[0];
  const int*   eidx     = (const int*)d_in[1];
  const int*   batch    = (const int*)d_in[2];
  const float* W_in     = (const float*)d_in[3];
  const float* W_conv   = (const float*)d_in[4];
  const float* W_out    = (const float*)d_in[5];
  const float* b_out    = (const float*)d_in[6];
  float* out            = (float*)d_out;

  const int* src = eidx;            // edge_index[0]
  const int* dst = eidx + N_EDGES;  // edge_index[1]

  float* ws = (float*)d_ws;
  float* H       = ws;                         // 1.6M floats
  float* T       = ws + 1600000;               // 1.6M floats
  int*   row_ptr = (int*)(ws + 3200000);       // 50001 (pad 50008)
  int*   deg     = row_ptr + 50008;            // 50000 (pad 50048)
  int*   cursor  = deg + 50048;                // 50000 (pad 50048)
  int*   bsum    = cursor + 50048;             // 256
  int*   adj     = bsum + 256;                 // 800000
  float* SUMS    = (float*)(adj + 800000);     // 4096
  float* CNT     = SUMS + 4096;                // 128

  const int kan_blocks  = 2 * ((N_NODES + 127) / 128);  // 782 (x2 o-halves)
  const int edge_blocks = (N_EDGES + 255) / 256;        // 3125
  const int gath_blocks = (N_NODES * 8 + 255) / 256;    // 1563

  const int WCONV_STRIDE = 2 * HIDDEN * HIDDEN * GRID_SZ;  // 8192

  // --- CSR build (multi-block scan; every kernel chip-wide)
  zero_int_kernel<<<SCAN_BLOCKS, 256, 0, stream>>>(deg, N_NODES);
  hist_kernel<<<edge_blocks, 256, 0, stream>>>(dst, deg);
  scanA_kernel<<<SCAN_BLOCKS, 256, 0, stream>>>(deg, bsum);
  scanB_kernel<<<1, 256, 0, stream>>>(bsum, row_ptr);
  scanC_kernel<<<SCAN_BLOCKS, 256, 0, stream>>>(deg, bsum, row_ptr, cursor);
  fill_kernel<<<edge_blocks, 256, 0, stream>>>(src, dst, cursor, adj);

  // --- input KAN projection: H = KAN_in(x)
  kan_input_v10<<<kan_blocks, 128, 0, stream>>>(x, W_in, H);

  // --- layer 0: T = KAN_0(H); H = leaky(H + gather(T))
  kan_node_v10<<<kan_blocks, 128, 0, stream>>>(H, W_conv, T);
  gather_update_v2<<<gath_blocks, 256, 0, stream>>>(T, row_ptr, adj, H);

  // --- layer 1
  kan_node_v10<<<kan_blocks, 128, 0, stream>>>(H, W_conv + WCONV_STRIDE, T);
  gather_update_v2<<<gath_blocks, 256, 0, stream>>>(T, row_ptr, adj, H);

  // --- pool + readout
  zero_kernel<<<17, 256, 0, stream>>>(SUMS, N_GRAPHS * HIDDEN + N_GRAPHS);
  pool_rl<<<POOL_RANGES / 8, 256, 0, stream>>>(H, batch, SUMS, CNT);
  readout_kernel<<<1, 128, 0, stream>>>(SUMS, CNT, W_out, b_out, out);
}